// Round 1
// baseline (968.775 us; speedup 1.0000x reference)
//
#include <hip/hip_runtime.h>
#include <math.h>

// Model: seq2seq LSTM w/ multiplicative attention, greedy decode.
// V=50257, H=1024, T=10. All fp32. Batch=1 -> matvec-dominated, no MFMA.
//
// Pipeline (33 kernel launches on `stream`, all graph-capture safe):
//   k_init                : gather x_seq = embeds[input_seq], zero h0/c
//   k_enc_step x10        : fused LSTM step (block j computes 4 gate dots + cell for unit j)
//   k_mt                  : MT[j][i] = dot(wa[i], enc_out[j])  (hoists wa out of the decode loop)
//   per decoder step t:
//     k_dec_a             : (redundant per block) argmax-finalize prev step -> prev embed,
//                           attention scores/softmax/ctx -> rnn_in in LDS,
//                           then gates + cell for unit j = blockIdx.x
//     k_logits            : out_w @ h + out_b -> d_out row t, per-block argmax partials
//   k_argmax_final        : finalize argmax of step 9 -> pred_seq[9]

#define H     1024
#define T     10
#define VOCAB 50257
#define NB_LOG 1024   // blocks in k_logits => 1024 argmax partials

__device__ __forceinline__ float sigmoidf_(float x) { return 1.f / (1.f + expf(-x)); }

__device__ __forceinline__ float dot4(float4 a, float4 b) {
    return a.x * b.x + a.y * b.y + a.z * b.z + a.w * b.w;
}

// ---------------------------------------------------------------- init
__global__ __launch_bounds__(256)
void k_init(const int* __restrict__ seq, const float* __restrict__ embeds,
            float* __restrict__ x_seq, float* __restrict__ h0, float* __restrict__ c)
{
    int i = blockIdx.x * 256 + threadIdx.x;
    // input_seq is jnp.int64 in the reference; harness doc says int -> const int*.
    // Sniff the layout: if the buffer is actually int64, all high words are 0.
    // (int32 layout would need tokens 1,3,5,7,9 all == 0: probability ~0.)
    bool w64 = (seq[1] == 0 && seq[3] == 0 && seq[5] == 0 && seq[7] == 0 && seq[9] == 0);
    if (i < T * H) {
        int t = i >> 10, e = i & (H - 1);
        int tok = w64 ? seq[2 * t] : seq[t];
        x_seq[i] = embeds[(size_t)tok * H + e];
    }
    if (i < H) { h0[i] = 0.f; c[i] = 0.f; }
}

// ---------------------------------------------------------------- encoder LSTM step
// grid = H blocks; block 256 = 4 waves; wave w computes gate w (rows w*H+j of both
// weight matrices, 1024-dot each); thread 0 does the cell update for unit j.
__global__ __launch_bounds__(256)
void k_enc_step(const float* __restrict__ w_ih, const float* __restrict__ w_hh,
                const float* __restrict__ b_ih, const float* __restrict__ b_hh,
                const float* __restrict__ x, const float* __restrict__ h_in,
                float* __restrict__ h_out, float* __restrict__ c,
                float* __restrict__ enc_row)
{
    const int j    = blockIdx.x;
    const int lane = threadIdx.x & 63;
    const int wave = threadIdx.x >> 6;
    const int row  = wave * H + j;

    const float4* wi = (const float4*)(w_ih + (size_t)row * H);
    const float4* wh = (const float4*)(w_hh + (size_t)row * H);
    const float4* x4 = (const float4*)x;
    const float4* h4 = (const float4*)h_in;

    float acc = 0.f;
    #pragma unroll
    for (int r = 0; r < 4; ++r) {
        float4 a  = wi[lane + r * 64], bx = x4[lane + r * 64];
        float4 a2 = wh[lane + r * 64], bh = h4[lane + r * 64];
        acc += dot4(a, bx) + dot4(a2, bh);
    }
    #pragma unroll
    for (int off = 32; off; off >>= 1) acc += __shfl_down(acc, off);

    __shared__ float g[4];
    if (lane == 0) g[wave] = acc + b_ih[row] + b_hh[row];
    __syncthreads();
    if (threadIdx.x == 0) {
        float gi = sigmoidf_(g[0]);
        float gf = sigmoidf_(g[1]);
        float gg = tanhf(g[2]);
        float go = sigmoidf_(g[3]);
        float cn = gf * c[j] + gi * gg;
        c[j] = cn;
        float hn = go * tanhf(cn);
        h_out[j]   = hn;
        enc_row[j] = hn;
    }
}

// ---------------------------------------------------------------- MT = (wa @ enc_out^T)^T
// MT[j*H + i] = dot(wa_row_i, enc_out_row_j).  grid = H/4 blocks, wave per wa row.
__global__ __launch_bounds__(256)
void k_mt(const float* __restrict__ wa, const float* __restrict__ enc_out,
          float* __restrict__ MT)
{
    const int lane = threadIdx.x & 63;
    const int wave = threadIdx.x >> 6;
    const int i    = blockIdx.x * 4 + wave;

    const float4* w4 = (const float4*)(wa + (size_t)i * H);
    float4 w[4];
    #pragma unroll
    for (int r = 0; r < 4; ++r) w[r] = w4[lane + r * 64];

    #pragma unroll
    for (int j = 0; j < T; ++j) {
        const float4* e4 = (const float4*)(enc_out + j * H);
        float acc = 0.f;
        #pragma unroll
        for (int r = 0; r < 4; ++r) acc += dot4(w[r], e4[lane + r * 64]);
        #pragma unroll
        for (int off = 32; off; off >>= 1) acc += __shfl_down(acc, off);
        if (lane == 0) MT[j * H + i] = acc;
    }
}

// ---------------------------------------------------------------- decoder phase A
// grid = H blocks. Each block (redundantly) finalizes the previous step's argmax,
// gathers prev embedding, computes attention (scores->softmax->ctx) into LDS rnn_in,
// then computes the 4 gate dots + cell update for unit j = blockIdx.x.
__global__ __launch_bounds__(256)
void k_dec_a(const float* __restrict__ w_ih, const float* __restrict__ w_hh,
             const float* __restrict__ b_ih, const float* __restrict__ b_hh,
             const float* __restrict__ embeds, const float* __restrict__ enc_out,
             const float* __restrict__ MT,
             const float* __restrict__ h_in, float* __restrict__ h_out,
             float* __restrict__ c,
             const float* __restrict__ pval, const int* __restrict__ pidx,
             float* __restrict__ pred_out,   // d_out slot for pred_seq[t-1]; null at t=0
             int t)
{
    const int tid  = threadIdx.x;
    const int lane = tid & 63;
    const int wave = tid >> 6;

    __shared__ __align__(16) float rnn_in[2 * H];
    __shared__ float s_a[T];
    __shared__ float s_red[4][T];
    __shared__ float s_wv[4];
    __shared__ int   s_wi[4];

    // ---- previous-step argmax -> feedback embedding (relu'd) ----
    if (t > 0) {
        float bv = -INFINITY; int bi = 0x7fffffff;
        for (int k = tid; k < NB_LOG; k += 256) {
            float v = pval[k]; int ix = pidx[k];
            if (v > bv || (v == bv && ix < bi)) { bv = v; bi = ix; }
        }
        #pragma unroll
        for (int off = 32; off; off >>= 1) {
            float ov = __shfl_down(bv, off);
            int   oi = __shfl_down(bi, off);
            if (ov > bv || (ov == bv && oi < bi)) { bv = ov; bi = oi; }
        }
        if (lane == 0) { s_wv[wave] = bv; s_wi[wave] = bi; }
        __syncthreads();
        float v = s_wv[0]; int b = s_wi[0];
        #pragma unroll
        for (int k = 1; k < 4; ++k)
            if (s_wv[k] > v || (s_wv[k] == v && s_wi[k] < b)) { v = s_wv[k]; b = s_wi[k]; }
        if (blockIdx.x == 0 && tid == 0) pred_out[0] = (float)b;
        const float* em = embeds + (size_t)b * H;
        for (int i = tid; i < H; i += 256) rnn_in[i] = fmaxf(em[i], 0.f);
    } else {
        for (int i = tid; i < H; i += 256) rnn_in[i] = 0.f;
    }

    // ---- attention scores: sc[j] = dot(h_in, MT[j]) ----
    float sc[T];
    #pragma unroll
    for (int j = 0; j < T; ++j) sc[j] = 0.f;
    for (int e = tid; e < H; e += 256) {
        float hv = h_in[e];
        #pragma unroll
        for (int j = 0; j < T; ++j) sc[j] += hv * MT[j * H + e];
    }
    #pragma unroll
    for (int j = 0; j < T; ++j) {
        float v = sc[j];
        #pragma unroll
        for (int off = 32; off; off >>= 1) v += __shfl_down(v, off);
        if (lane == 0) s_red[wave][j] = v;
    }
    __syncthreads();          // also orders rnn_in[0..H) writes before gate reads
    if (tid == 0) {
        float mx = -INFINITY; float tmp[T];
        #pragma unroll
        for (int j = 0; j < T; ++j) {
            float v = s_red[0][j] + s_red[1][j] + s_red[2][j] + s_red[3][j];
            tmp[j] = v; mx = fmaxf(mx, v);
        }
        float ssum = 0.f;
        #pragma unroll
        for (int j = 0; j < T; ++j) { float e = expf(tmp[j] - mx); s_a[j] = e; ssum += e; }
        float inv = 1.f / ssum;
        #pragma unroll
        for (int j = 0; j < T; ++j) s_a[j] *= inv;
    }
    __syncthreads();

    // ---- context vector into rnn_in[H..2H) ----
    for (int i = tid; i < H; i += 256) {
        float acc = 0.f;
        #pragma unroll
        for (int j = 0; j < T; ++j) acc += s_a[j] * enc_out[j * H + i];
        rnn_in[H + i] = acc;
    }
    __syncthreads();

    // ---- gates + cell for unit j = blockIdx.x ----
    const int j   = blockIdx.x;
    const int row = wave * H + j;
    float acc = 0.f;
    const float4* wi4 = (const float4*)(w_ih + (size_t)row * (2 * H));
    const float4* rn4 = (const float4*)rnn_in;
    #pragma unroll
    for (int r = 0; r < 8; ++r)
        acc += dot4(wi4[lane + r * 64], rn4[lane + r * 64]);
    const float4* wh4 = (const float4*)(w_hh + (size_t)row * H);
    const float4* h4  = (const float4*)h_in;
    #pragma unroll
    for (int r = 0; r < 4; ++r)
        acc += dot4(wh4[lane + r * 64], h4[lane + r * 64]);
    #pragma unroll
    for (int off = 32; off; off >>= 1) acc += __shfl_down(acc, off);

    __shared__ float g[4];
    if (lane == 0) g[wave] = acc + b_ih[row] + b_hh[row];
    __syncthreads();
    if (tid == 0) {
        float gi = sigmoidf_(g[0]);
        float gf = sigmoidf_(g[1]);
        float gg = tanhf(g[2]);
        float go = sigmoidf_(g[3]);
        float cn = gf * c[j] + gi * gg;
        c[j] = cn;
        h_out[j] = go * tanhf(cn);
    }
}

// ---------------------------------------------------------------- logits + argmax partials
// grid = NB_LOG blocks x 256. Wave wg handles rows [wg*4, wg*4+4) strided by 16384.
// h is held in registers (16 floats/lane); 16 float4 weight loads in flight per lane.
__global__ __launch_bounds__(256)
void k_logits(const float* __restrict__ out_w, const float* __restrict__ out_b,
              const float* __restrict__ h, float* __restrict__ logits,
              float* __restrict__ pval, int* __restrict__ pidx)
{
    const int lane = threadIdx.x & 63;
    const int wave = threadIdx.x >> 6;
    const int wg   = blockIdx.x * 4 + wave;    // 0..4095

    const float4* h4 = (const float4*)h;
    float4 hf[4];
    #pragma unroll
    for (int r = 0; r < 4; ++r) hf[r] = h4[lane + r * 64];

    float bv = -INFINITY; int bi = 0x7fffffff;

    for (int base = wg * 4; base < VOCAB; base += 4096 * 4) {
        #pragma unroll
        for (int rr = 0; rr < 4; ++rr) {
            int row  = base + rr;
            bool ok  = row < VOCAB;
            int rowc = ok ? row : 0;
            const float4* w4 = (const float4*)(out_w + (size_t)rowc * H);
            float acc = 0.f;
            #pragma unroll
            for (int r = 0; r < 4; ++r) acc += dot4(w4[lane + r * 64], hf[r]);
            #pragma unroll
            for (int off = 32; off; off >>= 1) acc += __shfl_down(acc, off);
            if (lane == 0 && ok) {
                float lv = acc + out_b[row];
                logits[row] = lv;
                if (lv > bv || (lv == bv && row < bi)) { bv = lv; bi = row; }
            }
        }
    }

    __shared__ float s_wv[4];
    __shared__ int   s_wi[4];
    if (lane == 0) { s_wv[wave] = bv; s_wi[wave] = bi; }
    __syncthreads();
    if (threadIdx.x == 0) {
        float v = s_wv[0]; int b = s_wi[0];
        #pragma unroll
        for (int k = 1; k < 4; ++k)
            if (s_wv[k] > v || (s_wv[k] == v && s_wi[k] < b)) { v = s_wv[k]; b = s_wi[k]; }
        pval[blockIdx.x] = v;
        pidx[blockIdx.x] = b;
    }
}

// ---------------------------------------------------------------- final argmax (step T-1)
__global__ __launch_bounds__(256)
void k_argmax_final(const float* __restrict__ pval, const int* __restrict__ pidx,
                    float* __restrict__ pred_out)
{
    const int tid  = threadIdx.x;
    const int lane = tid & 63;
    const int wave = tid >> 6;
    float bv = -INFINITY; int bi = 0x7fffffff;
    for (int k = tid; k < NB_LOG; k += 256) {
        float v = pval[k]; int ix = pidx[k];
        if (v > bv || (v == bv && ix < bi)) { bv = v; bi = ix; }
    }
    #pragma unroll
    for (int off = 32; off; off >>= 1) {
        float ov = __shfl_down(bv, off);
        int   oi = __shfl_down(bi, off);
        if (ov > bv || (ov == bv && oi < bi)) { bv = ov; bi = oi; }
    }
    __shared__ float s_wv[4];
    __shared__ int   s_wi[4];
    if (lane == 0) { s_wv[wave] = bv; s_wi[wave] = bi; }
    __syncthreads();
    if (tid == 0) {
        float v = s_wv[0]; int b = s_wi[0];
        #pragma unroll
        for (int k = 1; k < 4; ++k)
            if (s_wv[k] > v || (s_wv[k] == v && s_wi[k] < b)) { v = s_wv[k]; b = s_wi[k]; }
        pred_out[0] = (float)b;
    }
}

// ---------------------------------------------------------------- host
extern "C" void kernel_launch(void* const* d_in, const int* in_sizes, int n_in,
                              void* d_out, int out_size, void* d_ws, size_t ws_size,
                              hipStream_t stream)
{
    const int*   seq      = (const int*)  d_in[0];
    const float* embeds   = (const float*)d_in[1];
    const float* enc_w_ih = (const float*)d_in[2];
    const float* enc_w_hh = (const float*)d_in[3];
    const float* enc_b_ih = (const float*)d_in[4];
    const float* enc_b_hh = (const float*)d_in[5];
    const float* dec_w_ih = (const float*)d_in[6];
    const float* dec_w_hh = (const float*)d_in[7];
    const float* dec_b_ih = (const float*)d_in[8];
    const float* dec_b_hh = (const float*)d_in[9];
    const float* out_w    = (const float*)d_in[10];
    const float* out_b    = (const float*)d_in[11];
    const float* wa       = (const float*)d_in[12];

    float* out = (float*)d_out;            // [T*V logits][T pred ids as float]
    float* ws  = (float*)d_ws;
    float* x_seq  = ws;                    // 10240
    float* encout = ws + 10240;            // 10240
    float* hbuf0  = ws + 20480;            // 1024
    float* hbuf1  = ws + 21504;            // 1024
    float* cbuf   = ws + 22528;            // 1024
    float* MT     = ws + 23552;            // 10240
    float* pval   = ws + 33792;            // 1024
    int*   pidx   = (int*)(ws + 34816);    // 1024 ints

    k_init<<<(T * H + 255) / 256, 256, 0, stream>>>(seq, embeds, x_seq, hbuf0, cbuf);

    for (int t = 0; t < T; ++t) {
        float* hin  = (t & 1) ? hbuf1 : hbuf0;
        float* hout = (t & 1) ? hbuf0 : hbuf1;
        k_enc_step<<<H, 256, 0, stream>>>(enc_w_ih, enc_w_hh, enc_b_ih, enc_b_hh,
                                          x_seq + t * H, hin, hout, cbuf,
                                          encout + t * H);
    }
    // after step 9 (odd), final encoder h lives in hbuf0; c continues in cbuf.

    k_mt<<<H / 4, 256, 0, stream>>>(wa, encout, MT);

    for (int t = 0; t < T; ++t) {
        float* hin  = (t & 1) ? hbuf1 : hbuf0;
        float* hout = (t & 1) ? hbuf0 : hbuf1;
        k_dec_a<<<H, 256, 0, stream>>>(dec_w_ih, dec_w_hh, dec_b_ih, dec_b_hh,
                                       embeds, encout, MT, hin, hout, cbuf,
                                       pval, pidx,
                                       (t > 0) ? (out + (size_t)T * VOCAB + (t - 1)) : nullptr,
                                       t);
        k_logits<<<NB_LOG, 256, 0, stream>>>(out_w, out_b, hout,
                                             out + (size_t)t * VOCAB, pval, pidx);
    }
    k_argmax_final<<<1, 256, 0, stream>>>(pval, pidx, out + (size_t)T * VOCAB + (T - 1));
}

// Round 4
// 897.905 us; speedup vs baseline: 1.0789x; 1.0789x over previous
//
#include <hip/hip_runtime.h>
#include <math.h>

// Model: seq2seq LSTM w/ multiplicative attention, greedy decode.
// V=50257, H=1024, T=10. fp32 in/out; batch=1 -> matvec, no MFMA.
//
// Round-2 change (resubmitted rounds 3,4 after infra failures): out_w is
// converted to bf16 (RTNE) into d_ws once per call; the 10 logits matvecs read
// bf16 weights (halves the dominant traffic and makes the whole working set
// (~186 MB) LLC-resident).
//
// Pipeline (34 launches):
//   k_cvt                 : out_w fp32 -> bf16 in ws (103 MB)
//   k_init                : x_seq = embeds[input_seq], zero h0/c
//   k_enc_step x10        : fused LSTM step (block j = unit j, wave = gate)
//   k_mt                  : MT[j][i] = dot(wa_i, enc_out_j)  (hoists wa)
//   per decoder step t:
//     k_dec_a             : finalize prev argmax -> prev embed (redundant per
//                           block), attention -> rnn_in in LDS, gates + cell
//     k_logits            : bf16 out_w @ h + out_b -> d_out row t, argmax partials
//   k_argmax_final        : pred_seq[9]

#define H     1024
#define T     10
#define VOCAB 50257
#define NB_LOG 1024

__device__ __forceinline__ float sigmoidf_(float x) { return 1.f / (1.f + expf(-x)); }

__device__ __forceinline__ float dot4(float4 a, float4 b) {
    return a.x * b.x + a.y * b.y + a.z * b.z + a.w * b.w;
}

// round-to-nearest-even fp32 -> bf16 (top 16 bits)
__device__ __forceinline__ unsigned bf16r(float x) {
    unsigned u = __float_as_uint(x);
    return (u + 0x7fffu + ((u >> 16) & 1u)) >> 16;
}
__device__ __forceinline__ unsigned pack2(float lo, float hi) {
    return bf16r(lo) | (bf16r(hi) << 16);
}

// ---------------------------------------------------------------- out_w -> bf16
__global__ __launch_bounds__(256)
void k_cvt(const float4* __restrict__ in, uint4* __restrict__ out, int n)
{
    int stride = gridDim.x * 256;
    for (int i = blockIdx.x * 256 + threadIdx.x; i < n; i += stride) {
        float4 a = in[2 * i], b = in[2 * i + 1];
        uint4 o;
        o.x = pack2(a.x, a.y); o.y = pack2(a.z, a.w);
        o.z = pack2(b.x, b.y); o.w = pack2(b.z, b.w);
        out[i] = o;
    }
}

// ---------------------------------------------------------------- init
__global__ __launch_bounds__(256)
void k_init(const int* __restrict__ seq, const float* __restrict__ embeds,
            float* __restrict__ x_seq, float* __restrict__ h0, float* __restrict__ c)
{
    int i = blockIdx.x * 256 + threadIdx.x;
    // input_seq is int64 in the reference; sniff the layout (int64 -> odd words 0).
    bool w64 = (seq[1] == 0 && seq[3] == 0 && seq[5] == 0 && seq[7] == 0 && seq[9] == 0);
    if (i < T * H) {
        int t = i >> 10, e = i & (H - 1);
        int tok = w64 ? seq[2 * t] : seq[t];
        x_seq[i] = embeds[(size_t)tok * H + e];
    }
    if (i < H) { h0[i] = 0.f; c[i] = 0.f; }
}

// ---------------------------------------------------------------- encoder LSTM step
__global__ __launch_bounds__(256)
void k_enc_step(const float* __restrict__ w_ih, const float* __restrict__ w_hh,
                const float* __restrict__ b_ih, const float* __restrict__ b_hh,
                const float* __restrict__ x, const float* __restrict__ h_in,
                float* __restrict__ h_out, float* __restrict__ c,
                float* __restrict__ enc_row)
{
    const int j    = blockIdx.x;
    const int lane = threadIdx.x & 63;
    const int wave = threadIdx.x >> 6;
    const int row  = wave * H + j;

    const float4* wi = (const float4*)(w_ih + (size_t)row * H);
    const float4* wh = (const float4*)(w_hh + (size_t)row * H);
    const float4* x4 = (const float4*)x;
    const float4* h4 = (const float4*)h_in;

    float acc = 0.f;
    #pragma unroll
    for (int r = 0; r < 4; ++r) {
        float4 a  = wi[lane + r * 64], bx = x4[lane + r * 64];
        float4 a2 = wh[lane + r * 64], bh = h4[lane + r * 64];
        acc += dot4(a, bx) + dot4(a2, bh);
    }
    #pragma unroll
    for (int off = 32; off; off >>= 1) acc += __shfl_down(acc, off);

    __shared__ float g[4];
    if (lane == 0) g[wave] = acc + b_ih[row] + b_hh[row];
    __syncthreads();
    if (threadIdx.x == 0) {
        float gi = sigmoidf_(g[0]);
        float gf = sigmoidf_(g[1]);
        float gg = tanhf(g[2]);
        float go = sigmoidf_(g[3]);
        float cn = gf * c[j] + gi * gg;
        c[j] = cn;
        float hn = go * tanhf(cn);
        h_out[j]   = hn;
        enc_row[j] = hn;
    }
}

// ---------------------------------------------------------------- MT = (wa @ enc_out^T)^T
__global__ __launch_bounds__(256)
void k_mt(const float* __restrict__ wa, const float* __restrict__ enc_out,
          float* __restrict__ MT)
{
    const int lane = threadIdx.x & 63;
    const int wave = threadIdx.x >> 6;
    const int i    = blockIdx.x * 4 + wave;

    const float4* w4 = (const float4*)(wa + (size_t)i * H);
    float4 w[4];
    #pragma unroll
    for (int r = 0; r < 4; ++r) w[r] = w4[lane + r * 64];

    #pragma unroll
    for (int j = 0; j < T; ++j) {
        const float4* e4 = (const float4*)(enc_out + j * H);
        float acc = 0.f;
        #pragma unroll
        for (int r = 0; r < 4; ++r) acc += dot4(w[r], e4[lane + r * 64]);
        #pragma unroll
        for (int off = 32; off; off >>= 1) acc += __shfl_down(acc, off);
        if (lane == 0) MT[j * H + i] = acc;
    }
}

// ---------------------------------------------------------------- decoder phase A
__global__ __launch_bounds__(256)
void k_dec_a(const float* __restrict__ w_ih, const float* __restrict__ w_hh,
             const float* __restrict__ b_ih, const float* __restrict__ b_hh,
             const float* __restrict__ embeds, const float* __restrict__ enc_out,
             const float* __restrict__ MT,
             const float* __restrict__ h_in, float* __restrict__ h_out,
             float* __restrict__ c,
             const float* __restrict__ pval, const int* __restrict__ pidx,
             float* __restrict__ pred_out, int t)
{
    const int tid  = threadIdx.x;
    const int lane = tid & 63;
    const int wave = tid >> 6;

    __shared__ __align__(16) float rnn_in[2 * H];
    __shared__ float s_a[T];
    __shared__ float s_red[4][T];
    __shared__ float s_wv[4];
    __shared__ int   s_wi[4];

    if (t > 0) {
        float bv = -INFINITY; int bi = 0x7fffffff;
        for (int k = tid; k < NB_LOG; k += 256) {
            float v = pval[k]; int ix = pidx[k];
            if (v > bv || (v == bv && ix < bi)) { bv = v; bi = ix; }
        }
        #pragma unroll
        for (int off = 32; off; off >>= 1) {
            float ov = __shfl_down(bv, off);
            int   oi = __shfl_down(bi, off);
            if (ov > bv || (ov == bv && oi < bi)) { bv = ov; bi = oi; }
        }
        if (lane == 0) { s_wv[wave] = bv; s_wi[wave] = bi; }
        __syncthreads();
        float v = s_wv[0]; int b = s_wi[0];
        #pragma unroll
        for (int k = 1; k < 4; ++k)
            if (s_wv[k] > v || (s_wv[k] == v && s_wi[k] < b)) { v = s_wv[k]; b = s_wi[k]; }
        if (blockIdx.x == 0 && tid == 0) pred_out[0] = (float)b;
        const float* em = embeds + (size_t)b * H;
        for (int i = tid; i < H; i += 256) rnn_in[i] = fmaxf(em[i], 0.f);
    } else {
        for (int i = tid; i < H; i += 256) rnn_in[i] = 0.f;
    }

    // attention scores: sc[j] = dot(h_in, MT[j])
    float sc[T];
    #pragma unroll
    for (int j = 0; j < T; ++j) sc[j] = 0.f;
    for (int e = tid; e < H; e += 256) {
        float hv = h_in[e];
        #pragma unroll
        for (int j = 0; j < T; ++j) sc[j] += hv * MT[j * H + e];
    }
    #pragma unroll
    for (int j = 0; j < T; ++j) {
        float v = sc[j];
        #pragma unroll
        for (int off = 32; off; off >>= 1) v += __shfl_down(v, off);
        if (lane == 0) s_red[wave][j] = v;
    }
    __syncthreads();
    if (tid == 0) {
        float mx = -INFINITY; float tmp[T];
        #pragma unroll
        for (int j = 0; j < T; ++j) {
            float v = s_red[0][j] + s_red[1][j] + s_red[2][j] + s_red[3][j];
            tmp[j] = v; mx = fmaxf(mx, v);
        }
        float ssum = 0.f;
        #pragma unroll
        for (int j = 0; j < T; ++j) { float e = expf(tmp[j] - mx); s_a[j] = e; ssum += e; }
        float inv = 1.f / ssum;
        #pragma unroll
        for (int j = 0; j < T; ++j) s_a[j] *= inv;
    }
    __syncthreads();

    for (int i = tid; i < H; i += 256) {
        float acc = 0.f;
        #pragma unroll
        for (int j = 0; j < T; ++j) acc += s_a[j] * enc_out[j * H + i];
        rnn_in[H + i] = acc;
    }
    __syncthreads();

    const int j   = blockIdx.x;
    const int row = wave * H + j;
    float acc = 0.f;
    const float4* wi4 = (const float4*)(w_ih + (size_t)row * (2 * H));
    const float4* rn4 = (const float4*)rnn_in;
    #pragma unroll
    for (int r = 0; r < 8; ++r)
        acc += dot4(wi4[lane + r * 64], rn4[lane + r * 64]);
    const float4* wh4 = (const float4*)(w_hh + (size_t)row * H);
    const float4* h4  = (const float4*)h_in;
    #pragma unroll
    for (int r = 0; r < 4; ++r)
        acc += dot4(wh4[lane + r * 64], h4[lane + r * 64]);
    #pragma unroll
    for (int off = 32; off; off >>= 1) acc += __shfl_down(acc, off);

    __shared__ float g[4];
    if (lane == 0) g[wave] = acc + b_ih[row] + b_hh[row];
    __syncthreads();
    if (tid == 0) {
        float gi = sigmoidf_(g[0]);
        float gf = sigmoidf_(g[1]);
        float gg = tanhf(g[2]);
        float go = sigmoidf_(g[3]);
        float cn = gf * c[j] + gi * gg;
        c[j] = cn;
        h_out[j] = go * tanhf(cn);
    }
}

// ---------------------------------------------------------------- logits (bf16 weights)
// grid = NB_LOG x 256. Wave wg: rows [wg*4, wg*4+4) strided by 16384.
// Row = 1024 bf16 = 128 uint4; lane loads uint4 at (lane + half*64), half=0,1.
__global__ __launch_bounds__(256)
void k_logits(const uint4* __restrict__ ow, const float* __restrict__ out_b,
              const float* __restrict__ h, float* __restrict__ logits,
              float* __restrict__ pval, int* __restrict__ pidx)
{
    const int lane = threadIdx.x & 63;
    const int wave = threadIdx.x >> 6;
    const int wg   = blockIdx.x * 4 + wave;

    // h fragment: elems (lane + half*64)*8 + k, k=0..7
    float hf[2][8];
    const float4* h4 = (const float4*)h;
    #pragma unroll
    for (int half = 0; half < 2; ++half) {
        float4 a = h4[(lane + half * 64) * 2];
        float4 b = h4[(lane + half * 64) * 2 + 1];
        hf[half][0] = a.x; hf[half][1] = a.y; hf[half][2] = a.z; hf[half][3] = a.w;
        hf[half][4] = b.x; hf[half][5] = b.y; hf[half][6] = b.z; hf[half][7] = b.w;
    }

    float bv = -INFINITY; int bi = 0x7fffffff;

    for (int base = wg * 4; base < VOCAB; base += 4096 * 4) {
        #pragma unroll
        for (int rr = 0; rr < 4; ++rr) {
            int row  = base + rr;
            bool ok  = row < VOCAB;
            int rowc = ok ? row : 0;
            const uint4* wrow = ow + (size_t)rowc * 128;
            float acc = 0.f;
            #pragma unroll
            for (int half = 0; half < 2; ++half) {
                uint4 u = wrow[lane + half * 64];
                unsigned uu[4] = {u.x, u.y, u.z, u.w};
                #pragma unroll
                for (int q = 0; q < 4; ++q) {
                    float f0 = __uint_as_float(uu[q] << 16);
                    float f1 = __uint_as_float(uu[q] & 0xffff0000u);
                    acc += f0 * hf[half][2 * q] + f1 * hf[half][2 * q + 1];
                }
            }
            #pragma unroll
            for (int off = 32; off; off >>= 1) acc += __shfl_down(acc, off);
            if (lane == 0 && ok) {
                float lv = acc + out_b[row];
                logits[row] = lv;
                if (lv > bv || (lv == bv && row < bi)) { bv = lv; bi = row; }
            }
        }
    }

    __shared__ float s_wv[4];
    __shared__ int   s_wi[4];
    if (lane == 0) { s_wv[wave] = bv; s_wi[wave] = bi; }
    __syncthreads();
    if (threadIdx.x == 0) {
        float v = s_wv[0]; int b = s_wi[0];
        #pragma unroll
        for (int k = 1; k < 4; ++k)
            if (s_wv[k] > v || (s_wv[k] == v && s_wi[k] < b)) { v = s_wv[k]; b = s_wi[k]; }
        pval[blockIdx.x] = v;
        pidx[blockIdx.x] = b;
    }
}

// ---------------------------------------------------------------- final argmax
__global__ __launch_bounds__(256)
void k_argmax_final(const float* __restrict__ pval, const int* __restrict__ pidx,
                    float* __restrict__ pred_out)
{
    const int tid  = threadIdx.x;
    const int lane = tid & 63;
    const int wave = tid >> 6;
    float bv = -INFINITY; int bi = 0x7fffffff;
    for (int k = tid; k < NB_LOG; k += 256) {
        float v = pval[k]; int ix = pidx[k];
        if (v > bv || (v == bv && ix < bi)) { bv = v; bi = ix; }
    }
    #pragma unroll
    for (int off = 32; off; off >>= 1) {
        float ov = __shfl_down(bv, off);
        int   oi = __shfl_down(bi, off);
        if (ov > bv || (ov == bv && oi < bi)) { bv = ov; bi = oi; }
    }
    __shared__ float s_wv[4];
    __shared__ int   s_wi[4];
    if (lane == 0) { s_wv[wave] = bv; s_wi[wave] = bi; }
    __syncthreads();
    if (tid == 0) {
        float v = s_wv[0]; int b = s_wi[0];
        #pragma unroll
        for (int k = 1; k < 4; ++k)
            if (s_wv[k] > v || (s_wv[k] == v && s_wi[k] < b)) { v = s_wv[k]; b = s_wi[k]; }
        pred_out[0] = (float)b;
    }
}

// ---------------------------------------------------------------- host
extern "C" void kernel_launch(void* const* d_in, const int* in_sizes, int n_in,
                              void* d_out, int out_size, void* d_ws, size_t ws_size,
                              hipStream_t stream)
{
    const int*   seq      = (const int*)  d_in[0];
    const float* embeds   = (const float*)d_in[1];
    const float* enc_w_ih = (const float*)d_in[2];
    const float* enc_w_hh = (const float*)d_in[3];
    const float* enc_b_ih = (const float*)d_in[4];
    const float* enc_b_hh = (const float*)d_in[5];
    const float* dec_w_ih = (const float*)d_in[6];
    const float* dec_w_hh = (const float*)d_in[7];
    const float* dec_b_ih = (const float*)d_in[8];
    const float* dec_b_hh = (const float*)d_in[9];
    const float* out_w    = (const float*)d_in[10];
    const float* out_b    = (const float*)d_in[11];
    const float* wa       = (const float*)d_in[12];

    float* out = (float*)d_out;            // [T*V logits][T pred ids as float]
    float* ws  = (float*)d_ws;
    float* x_seq  = ws;                    // 10240
    float* encout = ws + 10240;            // 10240
    float* hbuf0  = ws + 20480;            // 1024
    float* hbuf1  = ws + 21504;            // 1024
    float* cbuf   = ws + 22528;            // 1024
    float* MT     = ws + 23552;            // 10240
    float* pval   = ws + 33792;            // 1024
    int*   pidx   = (int*)(ws + 34816);    // 1024
    uint4* owbf   = (uint4*)(ws + 36864);  // V*H bf16 = 103 MB (ws is ~800 MB)

    const int n_u4 = VOCAB * H / 8;        // 6,432,896
    k_cvt<<<2048, 256, 0, stream>>>((const float4*)out_w, owbf, n_u4);

    k_init<<<(T * H + 255) / 256, 256, 0, stream>>>(seq, embeds, x_seq, hbuf0, cbuf);

    for (int t = 0; t < T; ++t) {
        float* hin  = (t & 1) ? hbuf1 : hbuf0;
        float* hout = (t & 1) ? hbuf0 : hbuf1;
        k_enc_step<<<H, 256, 0, stream>>>(enc_w_ih, enc_w_hh, enc_b_ih, enc_b_hh,
                                          x_seq + t * H, hin, hout, cbuf,
                                          encout + t * H);
    }

    k_mt<<<H / 4, 256, 0, stream>>>(wa, encout, MT);

    for (int t = 0; t < T; ++t) {
        float* hin  = (t & 1) ? hbuf1 : hbuf0;
        float* hout = (t & 1) ? hbuf0 : hbuf1;
        k_dec_a<<<H, 256, 0, stream>>>(dec_w_ih, dec_w_hh, dec_b_ih, dec_b_hh,
                                       embeds, encout, MT, hin, hout, cbuf,
                                       pval, pidx,
                                       (t > 0) ? (out + (size_t)T * VOCAB + (t - 1)) : nullptr,
                                       t);
        k_logits<<<NB_LOG, 256, 0, stream>>>(owbf, out_b, hout,
                                             out + (size_t)t * VOCAB, pval, pidx);
    }
    k_argmax_final<<<1, 256, 0, stream>>>(pval, pidx, out + (size_t)T * VOCAB + (T - 1));
}